// Round 1
// baseline (1603.756 us; speedup 1.0000x reference)
//
#include <hip/hip_runtime.h>
#include <cstdint>
#include <cstddef>

typedef __attribute__((ext_vector_type(4))) float f32x4;
typedef __attribute__((ext_vector_type(8))) short s16x8;

#define MFMA16(a, b, c) __builtin_amdgcn_mfma_f32_16x16x32_bf16(a, b, c, 0, 0, 0)

// Split fp32 into bf16 hi + bf16 lo (truncation; residual < 2^-17 * |f|, and the
// truncation error has random sign w.r.t. the other operand -> no coherent bias).
__device__ __forceinline__ void bsplit(float f, unsigned short& h, unsigned short& l) {
  unsigned u = __float_as_uint(f);
  h = (unsigned short)(u >> 16);
  float hf = __uint_as_float(u & 0xffff0000u);
  l = (unsigned short)(__float_as_uint(f - hf) >> 16);
}

// Stage a 128-row x 32-col fp32 tile (row stride D, col offset k) into padded
// LDS bf16 hi/lo tiles (row stride 40 ushort = 80 B -> 2-way-max bank aliasing).
__device__ __forceinline__ void stage_tile(const float* __restrict__ base, int D, int k,
                                           unsigned short* ldsH, unsigned short* ldsL,
                                           int tid) {
#pragma unroll
  for (int v = 0; v < 4; ++v) {
    int flat = v * 256 + tid;      // 0..1023 ; 8 float4 per row
    int row = flat >> 3, kq = flat & 7;
    const float4 f = *(const float4*)(base + (size_t)row * D + k + kq * 4);
    ushort4 hh, ll;
    bsplit(f.x, hh.x, ll.x);
    bsplit(f.y, hh.y, ll.y);
    bsplit(f.z, hh.z, ll.z);
    bsplit(f.w, hh.w, ll.w);
    *(ushort4*)&ldsH[row * 40 + kq * 4] = hh;
    *(ushort4*)&ldsL[row * 40 + kq * 4] = ll;
  }
}

// out[m][n] += sum_k A[m][k] * W[n][k],  M=128, N=2048 fixed, split-K over grid.y.
// bf16x3: hi*hi + hi*lo + lo*hi into fp32 acc -> ~17-bit mantissa accuracy.
__global__ __launch_bounds__(256) void k_gemm(const float* __restrict__ A,
                                              const float* __restrict__ W,
                                              float* __restrict__ out,
                                              int D, int stepsPerChunk) {
  __shared__ __align__(16) unsigned short Ah[128 * 40], Al[128 * 40];
  __shared__ __align__(16) unsigned short Bh[128 * 40], Bl[128 * 40];
  const int tid = threadIdx.x;
  const int n0 = blockIdx.x * 128;
  const int totalSteps = D >> 5;
  const int s0 = blockIdx.y * stepsPerChunk;
  const int s1 = (s0 + stepsPerChunk < totalSteps) ? s0 + stepsPerChunk : totalSteps;
  const int wave = tid >> 6, lane = tid & 63;
  const int q = lane >> 4, li = lane & 15;
  const int wm = (wave >> 1) * 64, wn = (wave & 1) * 64;
  const float* bbase = W + (size_t)n0 * D;

  f32x4 acc[4][4] = {};

  for (int s = s0; s < s1; ++s) {
    const int k = s << 5;
    stage_tile(A, D, k, Ah, Al, tid);
    stage_tile(bbase, D, k, Bh, Bl, tid);
    __syncthreads();

    s16x8 a_h[4], a_l[4], b_h[4], b_l[4];
#pragma unroll
    for (int mt = 0; mt < 4; ++mt) {
      int m = wm + mt * 16 + li;
      a_h[mt] = *(const s16x8*)&Ah[m * 40 + q * 8];
      a_l[mt] = *(const s16x8*)&Al[m * 40 + q * 8];
    }
#pragma unroll
    for (int nt = 0; nt < 4; ++nt) {
      int n = wn + nt * 16 + li;
      b_h[nt] = *(const s16x8*)&Bh[n * 40 + q * 8];
      b_l[nt] = *(const s16x8*)&Bl[n * 40 + q * 8];
    }
#pragma unroll
    for (int mt = 0; mt < 4; ++mt)
#pragma unroll
      for (int nt = 0; nt < 4; ++nt) {
        acc[mt][nt] = MFMA16(a_h[mt], b_h[nt], acc[mt][nt]);
        acc[mt][nt] = MFMA16(a_h[mt], b_l[nt], acc[mt][nt]);
        acc[mt][nt] = MFMA16(a_l[mt], b_h[nt], acc[mt][nt]);
      }
    __syncthreads();
  }

#pragma unroll
  for (int mt = 0; mt < 4; ++mt)
#pragma unroll
    for (int nt = 0; nt < 4; ++nt)
#pragma unroll
      for (int r = 0; r < 4; ++r) {
        int m = wm + mt * 16 + q * 4 + r;
        int n = n0 + wn + nt * 16 + li;
        atomicAdd(&out[m * 2048 + n], acc[mt][nt][r]);
      }
}

// One LSTM layer recurrence. 32 blocks x 256 threads = 128 waves; wave wgl owns
// hidden units j0..j0+3 across all 4 gates (its 16 MFMA "n" columns = gate*4+jj,
// W rows gate*512 + j0 + jj). W_hh fragments (bf16 hi/lo) persist in VGPRs across
// all 16 timesteps. One agent-scope spin barrier per step (fresh counter per step).
__global__ __launch_bounds__(256) void k_rec(const float* __restrict__ xg,
                                             const float* __restrict__ Whh,
                                             const float* __restrict__ bih,
                                             const float* __restrict__ bhh,
                                             float* __restrict__ h_all,
                                             int* __restrict__ cnt) {
  __shared__ __align__(16) unsigned short Ah[16 * 520], Al[16 * 520];
  const int tid = threadIdx.x;
  const int lane = tid & 63, wave = tid >> 6;
  const int q = lane >> 4, li = lane & 15;
  const int g = li >> 2, jj = li & 3;
  const int wgl = blockIdx.x * 4 + wave;   // 0..127
  const int j0 = wgl * 4;
  const int row = g * 512 + j0 + jj;       // W_hh / bias / gate row for this lane

  for (int i = tid; i < 16 * 520; i += 256) { Ah[i] = 0; Al[i] = 0; }

  // Load this lane's W_hh fragments once (B-frag: lane&15 = n(row), k = q*8+j).
  s16x8 wh[16], wl[16];
#pragma unroll
  for (int ks = 0; ks < 16; ++ks) {
    float fv[8];
    *(float4*)&fv[0] = *(const float4*)(Whh + row * 512 + ks * 32 + q * 8);
    *(float4*)&fv[4] = *(const float4*)(Whh + row * 512 + ks * 32 + q * 8 + 4);
    s16x8 h8, l8;
#pragma unroll
    for (int j = 0; j < 8; ++j) {
      unsigned short h, l;
      bsplit(fv[j], h, l);
      h8[j] = (short)h;
      l8[j] = (short)l;
    }
    wh[ks] = h8;
    wl[ks] = l8;
  }
  const float bias = bih[row] + bhh[row];
  float c[4] = {0.f, 0.f, 0.f, 0.f};
  __syncthreads();

  for (int t = 0; t < 16; ++t) {
    if (t > 0) {
      if (tid == 0) {
        while (__hip_atomic_load(cnt + (t - 1), __ATOMIC_ACQUIRE,
                                 __HIP_MEMORY_SCOPE_AGENT) < (int)gridDim.x) {}
      }
      __syncthreads();
      // Stage h(t-1): 8x512 fp32 -> bf16 hi/lo A-tile (rows 8..15 stay zero).
#pragma unroll
      for (int v = 0; v < 4; ++v) {
        int flat = v * 256 + tid;   // 0..1023 ; 128 float4 per batch row
        int b = flat >> 7, kq = flat & 127;
        float4 f = *(const float4*)(h_all + (b * 16 + (t - 1)) * 512 + kq * 4);
        ushort4 hh, ll;
        bsplit(f.x, hh.x, ll.x);
        bsplit(f.y, hh.y, ll.y);
        bsplit(f.z, hh.z, ll.z);
        bsplit(f.w, hh.w, ll.w);
        *(ushort4*)&Ah[b * 520 + kq * 4] = hh;
        *(ushort4*)&Al[b * 520 + kq * 4] = ll;
      }
      __syncthreads();
    }

    f32x4 acc = {0.f, 0.f, 0.f, 0.f};
    if (t > 0) {
#pragma unroll
      for (int ks = 0; ks < 16; ++ks) {
        s16x8 ah = *(const s16x8*)&Ah[li * 520 + ks * 32 + q * 8];
        s16x8 al = *(const s16x8*)&Al[li * 520 + ks * 32 + q * 8];
        acc = MFMA16(ah, wh[ks], acc);
        acc = MFMA16(ah, wl[ks], acc);
        acc = MFMA16(al, wh[ks], acc);
      }
    }

    // acc row m = q*4+r is batch index (valid m<8); col = this lane's gate row.
    float val[4];
#pragma unroll
    for (int r = 0; r < 4; ++r) {
      int mrow = q * 4 + r;
      float pre = acc[r] + bias;
      if (mrow < 8) pre += xg[(mrow * 16 + t) * 2048 + row];
      val[r] = (g == 2) ? tanhf(pre) : 1.f / (1.f + __expf(-pre));
    }
    const int base = lane & 48;
#pragma unroll
    for (int r = 0; r < 4; ++r) {
      float iv = __shfl(val[r], base + 0 + jj);
      float fv = __shfl(val[r], base + 4 + jj);
      float gv = __shfl(val[r], base + 8 + jj);
      float ov = __shfl(val[r], base + 12 + jj);
      int mrow = q * 4 + r;
      if (g == 0 && mrow < 8) {
        c[r] = fv * c[r] + iv * gv;
        float hv = ov * tanhf(c[r]);
        h_all[(mrow * 16 + t) * 512 + j0 + jj] = hv;
      }
    }

    if (t < 15) {
      __threadfence();
      __syncthreads();
      if (tid == 0)
        __hip_atomic_fetch_add(cnt + t, 1, __ATOMIC_RELEASE, __HIP_MEMORY_SCOPE_AGENT);
    }
  }
}

__global__ void k_fc(const float* __restrict__ h_all, const float* __restrict__ fw,
                     const float* __restrict__ fb, float* __restrict__ out) {
  int b = blockIdx.x / 6, o = blockIdx.x % 6;
  int lane = threadIdx.x;
  const float* h = h_all + (b * 16 + 15) * 512;
  float s = 0.f;
  for (int j = lane; j < 512; j += 64) s += h[j] * fw[o * 512 + j];
#pragma unroll
  for (int off = 32; off; off >>= 1) s += __shfl_down(s, off);
  if (lane == 0) out[b * 6 + o] = s + fb[o];
}

extern "C" void kernel_launch(void* const* d_in, const int* in_sizes, int n_in,
                              void* d_out, int out_size, void* d_ws, size_t ws_size,
                              hipStream_t stream) {
  const float* x    = (const float*)d_in[0];
  const float* Wih0 = (const float*)d_in[1];
  const float* Whh0 = (const float*)d_in[2];
  const float* bih0 = (const float*)d_in[3];
  const float* bhh0 = (const float*)d_in[4];
  const float* Wih1 = (const float*)d_in[5];
  const float* Whh1 = (const float*)d_in[6];
  const float* bih1 = (const float*)d_in[7];
  const float* bhh1 = (const float*)d_in[8];
  const float* fcw  = (const float*)d_in[9];
  const float* fcb  = (const float*)d_in[10];
  float* out = (float*)d_out;

  char* ws = (char*)d_ws;
  size_t off = 0;
  auto alloc = [&](size_t bytes) -> void* {
    void* p = ws + off;
    off += (bytes + 255) & ~(size_t)255;
    return p;
  };
  float* xg0 = (float*)alloc(128 * 2048 * sizeof(float));  // 1 MB
  float* xg1 = (float*)alloc(128 * 2048 * sizeof(float));  // 1 MB
  int* cnt   = (int*)alloc(4096);                          // 2 x 16 step counters
  const size_t zeroBytes = off;                            // must be zeroed each call
  float* h0 = (float*)alloc(128 * 512 * sizeof(float));    // [B][T][H]
  float* h1 = (float*)alloc(128 * 512 * sizeof(float));
  (void)ws_size; (void)in_sizes; (void)n_in; (void)out_size;

  hipMemsetAsync(d_ws, 0, zeroBytes, stream);

  // Layer 0: xg0 = x @ W_ih0^T   (K = 113344 = 3542 k-steps; 77 chunks x 46)
  k_gemm<<<dim3(16, 77), 256, 0, stream>>>(x, Wih0, xg0, 113344, 46);
  k_rec<<<32, 256, 0, stream>>>(xg0, Whh0, bih0, bhh0, h0, cnt);

  // Layer 1: xg1 = h0 @ W_ih1^T  (K = 512 = 16 k-steps; 4 chunks x 4)
  k_gemm<<<dim3(16, 4), 256, 0, stream>>>(h0, Wih1, xg1, 512, 4);
  k_rec<<<32, 256, 0, stream>>>(xg1, Whh1, bih1, bhh1, h1, cnt + 16);

  k_fc<<<48, 64, 0, stream>>>(h1, fcw, fcb, out);
}